// Round 6
// baseline (1457.104 us; speedup 1.0000x reference)
//
#include <hip/hip_runtime.h>
#include <hip/hip_bf16.h>

// EquivariantProductBasisWithSelfMagmomBlock — round 6 (= round 3 kernel;
// rounds 3-5 never ran: GPU acquisition timeouts).
// Diagnosis from rounds 1-2: inputs AND output are float32 (identical absmax
// across two different implementations == bf16-written-into-f32-buffer
// scrambling signature). Output dtype follows detected input dtype.
// 1 block = 1 node, 128 threads. Scalar, correctness-first.

using bf16 = __hip_bfloat16;
#define NN 65536

__device__ int g_bf16;

__device__ __forceinline__ float b2f(unsigned short u) {
    return __uint_as_float(((unsigned)u) << 16);
}

// node_attrs is exact one-hot {0.0,1.0}. As f32, every even-indexed ushort
// (low mantissa half of 0.0/1.0) is 0x0000. As bf16, ~half the rows have the
// 1.0 (0x3F80) at an even ushort index. Scan first 8192 ushorts.
__global__ void detect_dtype(const unsigned short* na) {
    int t = threadIdx.x;
    int nz = 0;
    for (int i = 2 * t; i < 8192; i += 128) nz |= (na[i] != 0);
    unsigned long long b = __ballot(nz);
    if (t == 0) g_bf16 = (b != 0ull) ? 1 : 0;
}

template<bool BF16>
__global__ void epb_kernel(const void* p_nf, const void* p_sc, const void* p_na,
                           const void* p_inv, const void* p_ma,
                           const void* p_wsc0, const void* p_wsc1,
                           const void* p_w1, const void* p_w2, const void* p_w3,
                           const void* p_w4, const void* p_Wl0, const void* p_Wl1,
                           const void* p_Wo0, const void* p_Wo1, void* p_out)
{
    if ((g_bf16 != 0) != BF16) return;   // wrong-dtype variant: uniform early exit

    const int n = blockIdx.x;
    const int t = threadIdx.x;           // 0..127

    auto LD = [](const void* p, long idx) -> float {
        if constexpr (BF16) return b2f(((const unsigned short*)p)[idx]);
        else                return ((const float*)p)[idx];
    };

    __shared__ float sY0[128], sY1a[128], sY1b[128], sY1c[128];
    __shared__ float sM0[256], sM1a[256], sM1b[256], sM1c[256];
    __shared__ float sH[64], sG[64];

    // ---- element index from one-hot
    int e = 0;
    #pragma unroll
    for (int i = 0; i < 10; ++i)
        if (LD(p_na, (long)n * 10 + i) > 0.5f) e = i;

    // ---- per-channel polynomial basis (channel = t)
    const long nfb = (long)n * 512 + (long)t * 4;
    const float x0 = LD(p_nf, nfb + 0);
    const float xa = LD(p_nf, nfb + 1);
    const float xb = LD(p_nf, nfb + 2);
    const float xc = LD(p_nf, nfb + 3);
    const float n1 = xa * xa + xb * xb + xc * xc;
    const float x2 = x0 * x0;

    const float y0 = LD(p_wsc0, (e * 5 + 0) * 128 + t) * x0
                   + LD(p_wsc0, (e * 5 + 1) * 128 + t) * x2
                   + LD(p_wsc0, (e * 5 + 2) * 128 + t) * n1
                   + LD(p_wsc0, (e * 5 + 3) * 128 + t) * (x2 * x0)
                   + LD(p_wsc0, (e * 5 + 4) * 128 + t) * (x0 * n1);
    const float s1 = LD(p_wsc1, (e * 4 + 0) * 128 + t)
                   + LD(p_wsc1, (e * 4 + 1) * 128 + t) * x0
                   + LD(p_wsc1, (e * 4 + 2) * 128 + t) * x2
                   + LD(p_wsc1, (e * 4 + 3) * 128 + t) * n1;
    const float y1a = s1 * xa, y1b = s1 * xb, y1c = s1 * xc;

    sY0[t] = y0; sY1a[t] = y1a; sY1b[t] = y1b; sY1c[t] = y1c;

    // ---- MLP 16 -> 64 -> 64 -> 64 (SiLU), then 64 -> 512 columns {t,128+t,256+t,384+t}
    if (t < 64) {
        float a = 0.f;
        for (int i = 0; i < 16; ++i) a += LD(p_inv, (long)n * 16 + i) * LD(p_w1, i * 64 + t);
        sH[t] = a / (1.0f + __expf(-a));
    }
    __syncthreads();
    if (t < 64) {
        float a = 0.f;
        for (int i = 0; i < 64; ++i) a += sH[i] * LD(p_w2, i * 64 + t);
        sG[t] = a / (1.0f + __expf(-a));
    }
    __syncthreads();
    if (t < 64) {
        float a = 0.f;
        for (int i = 0; i < 64; ++i) a += sG[i] * LD(p_w3, i * 64 + t);
        sH[t] = a / (1.0f + __expf(-a));
    }
    __syncthreads();

    float wa = 0.f, wb = 0.f, wc = 0.f, wd = 0.f;
    for (int i = 0; i < 64; ++i) {
        const float h = sH[i];
        wa += h * LD(p_w4, (long)i * 512 + t);
        wb += h * LD(p_w4, (long)i * 512 + 128 + t);
        wc += h * LD(p_w4, (long)i * 512 + 256 + t);
        wd += h * LD(p_w4, (long)i * 512 + 384 + t);
    }

    const float a0 = LD(p_ma, (long)n * 4 + 0);
    const float q1 = LD(p_ma, (long)n * 4 + 1);
    const float q2 = LD(p_ma, (long)n * 4 + 2);
    const float q3 = LD(p_ma, (long)n * 4 + 3);
    const float dt = xa * q1 + xb * q2 + xc * q3;

    sM0[t]        = wa * y0 * a0;        // mid0a
    sM0[128 + t]  = wb * s1 * dt;        // mid0b
    sM1a[t]       = wc * y0 * q1;        // mid1c m=0
    sM1b[t]       = wc * y0 * q2;
    sM1c[t]       = wc * y0 * q3;
    sM1a[128 + t] = wd * y1a * a0;       // mid1d m=0
    sM1b[128 + t] = wd * y1b * a0;
    sM1c[128 + t] = wd * y1c * a0;
    __syncthreads();

    // ---- output column d = t
    const int d = t;
    float o0 = LD(p_sc, (long)n * 512 + d);
    float oa = LD(p_sc, (long)n * 512 + 128 + 3 * d + 0);
    float ob = LD(p_sc, (long)n * 512 + 128 + 3 * d + 1);
    float oc = LD(p_sc, (long)n * 512 + 128 + 3 * d + 2);

    for (int k = 0; k < 256; ++k) {
        const float wl0 = LD(p_Wl0, (long)k * 128 + d);
        const float wl1 = LD(p_Wl1, (long)k * 128 + d);
        o0 += sM0[k]  * wl0;
        oa += sM1a[k] * wl1;
        ob += sM1b[k] * wl1;
        oc += sM1c[k] * wl1;
    }
    for (int k = 0; k < 128; ++k) {
        const float wo0 = LD(p_Wo0, (long)k * 128 + d);
        const float wo1 = LD(p_Wo1, (long)k * 128 + d);
        o0 += sY0[k]  * wo0;
        oa += sY1a[k] * wo1;
        ob += sY1b[k] * wo1;
        oc += sY1c[k] * wo1;
    }

    const long q = (long)n * 512;
    if constexpr (BF16) {
        bf16* out = (bf16*)p_out;
        out[q + d]             = __float2bfloat16(o0);
        out[q + 128 + 3*d + 0] = __float2bfloat16(oa);
        out[q + 128 + 3*d + 1] = __float2bfloat16(ob);
        out[q + 128 + 3*d + 2] = __float2bfloat16(oc);
    } else {
        float* out = (float*)p_out;
        out[q + d]             = o0;
        out[q + 128 + 3*d + 0] = oa;
        out[q + 128 + 3*d + 1] = ob;
        out[q + 128 + 3*d + 2] = oc;
    }
}

extern "C" void kernel_launch(void* const* d_in, const int* in_sizes, int n_in,
                              void* d_out, int out_size, void* d_ws, size_t ws_size,
                              hipStream_t stream) {
    (void)in_sizes; (void)n_in; (void)d_ws; (void)ws_size; (void)out_size;

    detect_dtype<<<1, 64, 0, stream>>>((const unsigned short*)d_in[2]);

    epb_kernel<false><<<NN, 128, 0, stream>>>(d_in[0], d_in[1], d_in[2], d_in[3], d_in[4],
                                              d_in[5], d_in[6], d_in[7], d_in[8], d_in[9],
                                              d_in[10], d_in[11], d_in[12], d_in[13], d_in[14],
                                              d_out);
    epb_kernel<true><<<NN, 128, 0, stream>>>(d_in[0], d_in[1], d_in[2], d_in[3], d_in[4],
                                             d_in[5], d_in[6], d_in[7], d_in[8], d_in[9],
                                             d_in[10], d_in[11], d_in[12], d_in[13], d_in[14],
                                             d_out);
}

// Round 8
// 910.819 us; speedup vs baseline: 1.5998x; 1.5998x over previous
//
#include <hip/hip_runtime.h>
#include <hip/hip_bf16.h>

// EquivariantProductBasisWithSelfMagmomBlock — round 8 (= round 7 resubmitted;
// round 7 never ran: container-level infra failure, kernel audited clean for
// OOB/hang/capture violations).
// Confirmed world (round 6 pass): f32 inputs, f32 output, absmax residue 0.03 = ref bf16 grid.
// Pipeline: convw (weights->bf16 [col][k]) ; prep (verified per-node math -> A rows bf16 in ws) ;
// gemm (M=262144, K=384, N=128, mfma_f32_16x16x32_bf16, f32 accum, +sc epilogue).
// ws layout (ushorts): WT0[128][384]@0, WT1@49152, A0[65536][384]@98304, A1[196608][384]@25264128.
// ws bytes needed: 201523200. Fallback to round-6 scalar kernel if ws too small.

typedef unsigned short u16;
typedef __attribute__((ext_vector_type(8))) short short8;
typedef __attribute__((ext_vector_type(4))) float f32x4;

#define NN 65536
#define WT1_OFF   49152u        // 128*384
#define A0_OFF    98304u        // 2*128*384
#define A1_OFF    25264128u     // A0_OFF + 65536*384
#define WS_NEEDED 201523200ull  // (A1_OFF + 196608*384) * 2 bytes

__device__ __forceinline__ u16 f2b(float f) {     // RNE f32 -> bf16 bits
    union { float f; unsigned u; } v; v.f = f;
    unsigned r = v.u + 0x7FFFu + ((v.u >> 16) & 1u);
    return (u16)(r >> 16);
}
__device__ __forceinline__ float silu_f(float x) { return x / (1.0f + __expf(-x)); }

// ---------------- kernel 1: weights -> bf16, transposed to [col][k] (k contiguous)
__global__ void convw(const float* Wl0, const float* Wl1,
                      const float* Wo0, const float* Wo1, u16* ws) {
    const int b   = blockIdx.x;          // 0..255
    const int mat = b >> 7, d = b & 127;
    const int k   = threadIdx.x;         // 0..383
    const float* Wl = mat ? Wl1 : Wl0;
    const float* Wo = mat ? Wo1 : Wo0;
    const float v = (k < 256) ? Wl[k * 128 + d] : Wo[(k - 256) * 128 + d];
    ws[(size_t)mat * WT1_OFF + (size_t)d * 384 + k] = f2b(v);
}

// ---------------- kernel 2: per-node math (verified round 6), A rows -> ws (bf16)
__global__ __launch_bounds__(256)
void prep(const float* nf, const float* na, const float* inv, const float* ma,
          const float* wsc0, const float* wsc1,
          const float* w1, const float* w2, const float* w3, const float* w4,
          u16* ws)
{
    const int t  = threadIdx.x;          // 0..127 channel
    const int ty = threadIdx.y;          // 0..1 node-in-block
    const int n  = blockIdx.x * 2 + ty;

    __shared__ float sH[2][64], sG[2][64];

    int e = 0;
    #pragma unroll
    for (int i = 0; i < 10; ++i) if (na[(size_t)n * 10 + i] > 0.5f) e = i;

    const float4 x = *(const float4*)(nf + (size_t)n * 512 + t * 4);
    const float x0 = x.x, xa = x.y, xb = x.z, xc = x.w;
    const float n1 = xa * xa + xb * xb + xc * xc;
    const float x2 = x0 * x0;

    const float y0 = wsc0[(e * 5 + 0) * 128 + t] * x0
                   + wsc0[(e * 5 + 1) * 128 + t] * x2
                   + wsc0[(e * 5 + 2) * 128 + t] * n1
                   + wsc0[(e * 5 + 3) * 128 + t] * (x2 * x0)
                   + wsc0[(e * 5 + 4) * 128 + t] * (x0 * n1);
    const float s1 = wsc1[(e * 4 + 0) * 128 + t]
                   + wsc1[(e * 4 + 1) * 128 + t] * x0
                   + wsc1[(e * 4 + 2) * 128 + t] * x2
                   + wsc1[(e * 4 + 3) * 128 + t] * n1;
    const float y1a = s1 * xa, y1b = s1 * xb, y1c = s1 * xc;

    if (t < 64) {
        float a = 0.f;
        #pragma unroll
        for (int i = 0; i < 16; ++i) a += inv[(size_t)n * 16 + i] * w1[i * 64 + t];
        sH[ty][t] = silu_f(a);
    }
    __syncthreads();
    if (t < 64) {
        float a = 0.f;
        for (int i = 0; i < 64; ++i) a += sH[ty][i] * w2[i * 64 + t];
        sG[ty][t] = silu_f(a);
    }
    __syncthreads();
    if (t < 64) {
        float a = 0.f;
        for (int i = 0; i < 64; ++i) a += sG[ty][i] * w3[i * 64 + t];
        sH[ty][t] = silu_f(a);
    }
    __syncthreads();

    float wa = 0.f, wb = 0.f, wc = 0.f, wd = 0.f;
    for (int i = 0; i < 64; ++i) {
        const float h = sH[ty][i];
        wa += h * w4[(size_t)i * 512 + t];
        wb += h * w4[(size_t)i * 512 + 128 + t];
        wc += h * w4[(size_t)i * 512 + 256 + t];
        wd += h * w4[(size_t)i * 512 + 384 + t];
    }

    const float a0 = ma[(size_t)n * 4 + 0];
    const float q1 = ma[(size_t)n * 4 + 1];
    const float q2 = ma[(size_t)n * 4 + 2];
    const float q3 = ma[(size_t)n * 4 + 3];
    const float dt = xa * q1 + xb * q2 + xc * q3;

    // A0 row n: [mid0a | mid0b | y0]
    u16* A0 = ws + A0_OFF + (size_t)n * 384;
    A0[t]       = f2b(wa * y0 * a0);
    A0[128 + t] = f2b(wb * s1 * dt);
    A0[256 + t] = f2b(y0);

    // A1 rows (n*3+m): [wc*y0*q_m | wd*y1m*a0 | y1m]
    u16* A1 = ws + A1_OFF + (size_t)(n * 3) * 384;
    A1[t]             = f2b(wc * y0 * q1);
    A1[128 + t]       = f2b(wd * y1a * a0);
    A1[256 + t]       = f2b(y1a);
    A1[384 + t]       = f2b(wc * y0 * q2);
    A1[384 + 128 + t] = f2b(wd * y1b * a0);
    A1[384 + 256 + t] = f2b(y1b);
    A1[768 + t]       = f2b(wc * y0 * q3);
    A1[768 + 128 + t] = f2b(wd * y1c * a0);
    A1[768 + 256 + t] = f2b(y1c);
}

// ---------------- kernel 3: MFMA GEMM, fragments straight from ws, +sc epilogue
__global__ __launch_bounds__(256)
void gemm(const u16* ws, const float* sc, float* out)
{
    const int w  = threadIdx.x >> 6;     // wave 0..3
    const int l  = threadIdx.x & 63;
    const int lr = l & 15;               // row/col-in-tile
    const int lk = l >> 4;               // k-chunk 0..3

    const int  blk  = blockIdx.x;        // 0..2047 ; 0..511 = A0, rest = A1
    const bool isA0 = blk < 512;
    const size_t Abase = isA0 ? (A0_OFF + (size_t)blk * 128 * 384)
                              : (A1_OFF + (size_t)(blk - 512) * 128 * 384);
    const u16* WT = ws + (isA0 ? 0u : WT1_OFF);

    f32x4 acc[2][8];
    #pragma unroll
    for (int a = 0; a < 2; ++a)
        #pragma unroll
        for (int b = 0; b < 8; ++b) acc[a][b] = (f32x4){0.f, 0.f, 0.f, 0.f};

    const u16* Ar0 = ws + Abase + (size_t)(w * 32 + lr) * 384 + lk * 8;
    const u16* Ar1 = Ar0 + 16 * 384;
    const u16* Bc  = WT + (size_t)lr * 384 + lk * 8;

    for (int kk = 0; kk < 384; kk += 32) {
        const short8 a0 = *(const short8*)(Ar0 + kk);
        const short8 a1 = *(const short8*)(Ar1 + kk);
        #pragma unroll
        for (int ct = 0; ct < 8; ++ct) {
            const short8 b = *(const short8*)(Bc + (size_t)ct * 6144 + kk);  // col += 16 -> +16*384
            acc[0][ct] = __builtin_amdgcn_mfma_f32_16x16x32_bf16(a0, b, acc[0][ct], 0, 0, 0);
            acc[1][ct] = __builtin_amdgcn_mfma_f32_16x16x32_bf16(a1, b, acc[1][ct], 0, 0, 0);
        }
    }

    // C/D layout (m89-verified): col = lane&15, row = (lane>>4)*4 + reg
    #pragma unroll
    for (int rt = 0; rt < 2; ++rt) {
        #pragma unroll
        for (int ct = 0; ct < 8; ++ct) {
            #pragma unroll
            for (int i = 0; i < 4; ++i) {
                const int row = blk * 128 + w * 32 + rt * 16 + lk * 4 + i;
                const int d   = ct * 16 + lr;
                const float v = acc[rt][ct][i];
                if (isA0) {
                    const size_t idx = (size_t)row * 512 + d;
                    out[idx] = v + sc[idx];
                } else {
                    const int r = row - NN;
                    const int n = r / 3, m = r - 3 * (r / 3);
                    const size_t idx = (size_t)n * 512 + 128 + 3 * d + m;
                    out[idx] = v + sc[idx];
                }
            }
        }
    }
}

// ---------------- fallback: verified round-6 scalar kernel (f32 hardcoded)
__global__ void epb_fallback(const float* nf, const float* sc, const float* na,
                             const float* inv, const float* ma,
                             const float* wsc0, const float* wsc1,
                             const float* w1, const float* w2, const float* w3,
                             const float* w4, const float* Wl0, const float* Wl1,
                             const float* Wo0, const float* Wo1, float* out)
{
    const int n = blockIdx.x;
    const int t = threadIdx.x;

    __shared__ float sY0[128], sY1a[128], sY1b[128], sY1c[128];
    __shared__ float sM0[256], sM1a[256], sM1b[256], sM1c[256];
    __shared__ float sH[64], sG[64];

    int e = 0;
    #pragma unroll
    for (int i = 0; i < 10; ++i) if (na[(size_t)n * 10 + i] > 0.5f) e = i;

    const float4 x = *(const float4*)(nf + (size_t)n * 512 + t * 4);
    const float x0 = x.x, xa = x.y, xb = x.z, xc = x.w;
    const float n1 = xa * xa + xb * xb + xc * xc;
    const float x2 = x0 * x0;

    const float y0 = wsc0[(e*5+0)*128+t]*x0 + wsc0[(e*5+1)*128+t]*x2 + wsc0[(e*5+2)*128+t]*n1
                   + wsc0[(e*5+3)*128+t]*(x2*x0) + wsc0[(e*5+4)*128+t]*(x0*n1);
    const float s1 = wsc1[(e*4+0)*128+t] + wsc1[(e*4+1)*128+t]*x0
                   + wsc1[(e*4+2)*128+t]*x2 + wsc1[(e*4+3)*128+t]*n1;
    const float y1a = s1*xa, y1b = s1*xb, y1c = s1*xc;
    sY0[t] = y0; sY1a[t] = y1a; sY1b[t] = y1b; sY1c[t] = y1c;

    if (t < 64) { float a=0.f; for (int i=0;i<16;++i) a += inv[(size_t)n*16+i]*w1[i*64+t]; sH[t]=silu_f(a); }
    __syncthreads();
    if (t < 64) { float a=0.f; for (int i=0;i<64;++i) a += sH[i]*w2[i*64+t]; sG[t]=silu_f(a); }
    __syncthreads();
    if (t < 64) { float a=0.f; for (int i=0;i<64;++i) a += sG[i]*w3[i*64+t]; sH[t]=silu_f(a); }
    __syncthreads();

    float wa=0.f, wb=0.f, wc=0.f, wd=0.f;
    for (int i = 0; i < 64; ++i) {
        const float h = sH[i];
        wa += h*w4[(size_t)i*512+t]; wb += h*w4[(size_t)i*512+128+t];
        wc += h*w4[(size_t)i*512+256+t]; wd += h*w4[(size_t)i*512+384+t];
    }

    const float a0 = ma[(size_t)n*4+0], q1 = ma[(size_t)n*4+1], q2 = ma[(size_t)n*4+2], q3 = ma[(size_t)n*4+3];
    const float dt = xa*q1 + xb*q2 + xc*q3;

    sM0[t] = wa*y0*a0; sM0[128+t] = wb*s1*dt;
    sM1a[t] = wc*y0*q1; sM1b[t] = wc*y0*q2; sM1c[t] = wc*y0*q3;
    sM1a[128+t] = wd*y1a*a0; sM1b[128+t] = wd*y1b*a0; sM1c[128+t] = wd*y1c*a0;
    __syncthreads();

    const int d = t;
    float o0 = sc[(size_t)n*512+d];
    float oa = sc[(size_t)n*512+128+3*d+0];
    float ob = sc[(size_t)n*512+128+3*d+1];
    float oc = sc[(size_t)n*512+128+3*d+2];
    for (int k = 0; k < 256; ++k) {
        const float wl0 = Wl0[k*128+d], wl1 = Wl1[k*128+d];
        o0 += sM0[k]*wl0; oa += sM1a[k]*wl1; ob += sM1b[k]*wl1; oc += sM1c[k]*wl1;
    }
    for (int k = 0; k < 128; ++k) {
        const float wo0 = Wo0[k*128+d], wo1 = Wo1[k*128+d];
        o0 += sY0[k]*wo0; oa += sY1a[k]*wo1; ob += sY1b[k]*wo1; oc += sY1c[k]*wo1;
    }
    const size_t q = (size_t)n * 512;
    out[q+d] = o0; out[q+128+3*d+0] = oa; out[q+128+3*d+1] = ob; out[q+128+3*d+2] = oc;
}

extern "C" void kernel_launch(void* const* d_in, const int* in_sizes, int n_in,
                              void* d_out, int out_size, void* d_ws, size_t ws_size,
                              hipStream_t stream) {
    (void)in_sizes; (void)n_in; (void)out_size;
    const float* nf   = (const float*)d_in[0];
    const float* sc   = (const float*)d_in[1];
    const float* na   = (const float*)d_in[2];
    const float* inv  = (const float*)d_in[3];
    const float* ma   = (const float*)d_in[4];
    const float* wsc0 = (const float*)d_in[5];
    const float* wsc1 = (const float*)d_in[6];
    const float* w1   = (const float*)d_in[7];
    const float* w2   = (const float*)d_in[8];
    const float* w3   = (const float*)d_in[9];
    const float* w4   = (const float*)d_in[10];
    const float* Wl0  = (const float*)d_in[11];
    const float* Wl1  = (const float*)d_in[12];
    const float* Wo0  = (const float*)d_in[13];
    const float* Wo1  = (const float*)d_in[14];
    float* out = (float*)d_out;

    if (ws_size >= WS_NEEDED) {
        u16* ws = (u16*)d_ws;
        convw<<<256, 384, 0, stream>>>(Wl0, Wl1, Wo0, Wo1, ws);
        prep<<<NN / 2, dim3(128, 2), 0, stream>>>(nf, na, inv, ma, wsc0, wsc1,
                                                  w1, w2, w3, w4, ws);
        gemm<<<2048, 256, 0, stream>>>(ws, sc, out);
    } else {
        epb_fallback<<<NN, 128, 0, stream>>>(nf, sc, na, inv, ma, wsc0, wsc1,
                                             w1, w2, w3, w4, Wl0, Wl1, Wo0, Wo1, out);
    }
}

// Round 9
// 726.410 us; speedup vs baseline: 2.0059x; 1.2539x over previous
//
#include <hip/hip_runtime.h>
#include <hip/hip_bf16.h>

// EquivariantProductBasisWithSelfMagmomBlock — round 9.
// Round-8 post-mortem: prep 453us (latency-bound on per-block w4 re-reads + scalar GEMV),
// gemm ~450us (stride-12 scattered epilogue on the A1 3/4 of blocks).
// New pipeline: convw/convw4 ; mlp (LDS weights, h -> split bf16 hi/lo, K=128) ;
// prep1 (y0/y1 only) ; tpwA (MFMA h2@w4T2, epilogue builds A products in-place) ;
// gemm0 (o0, coalesced) ; gemm1 (A1 m-major, 3-way B reuse, LDS-staged float4 epilogue).
// Fallbacks: round-8 path (ws >= 201.5MB), scalar (else).

typedef unsigned short u16;
typedef __attribute__((ext_vector_type(8))) short short8;
typedef __attribute__((ext_vector_type(4))) float f32x4;

#define NN 65536

// ---- new-path ws layout (u16 units) ----
constexpr size_t OFF_WT0 = 0;          // [128][384]
constexpr size_t OFF_WT1 = 49152;      // [128][384]
constexpr size_t OFF_W4T = 98304;      // [512][128]  (k>=64 duplicates k-64)
constexpr size_t OFF_H2  = 163840;     // [65536][128] (hi|lo)
constexpr size_t OFF_A0  = 8552448;    // [65536][384]
constexpr size_t OFF_A1  = 33718272;   // [3][65536][384]
constexpr size_t A1SZ    = 25165824;   // 65536*384
constexpr size_t WS2_NEEDED = 218431488ull;  // bytes
// ---- legacy (round-8) layout ----
constexpr size_t A0_OFF8 = 98304;
constexpr size_t A1_OFF8 = 25264128;
constexpr size_t WS8_NEEDED = 201523200ull;

__device__ __forceinline__ u16 f2b(float f) {
    union { float f; unsigned u; } v; v.f = f;
    unsigned r = v.u + 0x7FFFu + ((v.u >> 16) & 1u);
    return (u16)(r >> 16);
}
__device__ __forceinline__ float b2f(u16 u) {
    return __uint_as_float(((unsigned)u) << 16);
}
__device__ __forceinline__ float silu_f(float x) { return x / (1.0f + __expf(-x)); }

// ---------------- WT0/WT1: [col][k] bf16 of [W_l;Wo] ----------------
__global__ void convw(const float* Wl0, const float* Wl1,
                      const float* Wo0, const float* Wo1, u16* ws) {
    const int b   = blockIdx.x;          // 0..255
    const int mat = b >> 7, d = b & 127;
    const int k   = threadIdx.x;         // 0..383
    const float* Wl = mat ? Wl1 : Wl0;
    const float* Wo = mat ? Wo1 : Wo0;
    const float v = (k < 256) ? Wl[k * 128 + d] : Wo[(k - 256) * 128 + d];
    ws[(size_t)mat * OFF_WT1 + (size_t)d * 384 + k] = f2b(v);
}

// ---------------- w4T2: [col 512][k 128], rows k>=64 duplicate k-64 ----------------
__global__ void convw4(const float* w4, u16* ws) {
    const int c = blockIdx.x;            // 0..511
    const int k = threadIdx.x;           // 0..127
    ws[OFF_W4T + (size_t)c * 128 + k] = f2b(w4[(size_t)(k & 63) * 512 + c]);
}

// ---------------- mlp: inv -> h (3 silu layers), store hi/lo bf16 split ----------------
__global__ __launch_bounds__(256)
void mlp(const float* inv, const float* w1, const float* w2, const float* w3, u16* ws)
{
    __shared__ float sW1[16 * 64], sW2[64 * 64], sW3[64 * 64];
    __shared__ float sA[4][64], sB[4][64];
    const int t = threadIdx.x;
    for (int i = t; i < 16 * 64; i += 256) sW1[i] = w1[i];
    for (int i = t; i < 64 * 64; i += 256) sW2[i] = w2[i];
    for (int i = t; i < 64 * 64; i += 256) sW3[i] = w3[i];
    __syncthreads();
    const int g = t >> 6, j = t & 63;
    for (int it = 0; it < 8; ++it) {
        const int n = blockIdx.x * 32 + it * 4 + g;
        float a = 0.f;
        #pragma unroll
        for (int i = 0; i < 16; ++i) a += inv[(size_t)n * 16 + i] * sW1[i * 64 + j];
        sA[g][j] = silu_f(a);
        __syncthreads();
        float b = 0.f;
        #pragma unroll 8
        for (int i = 0; i < 64; ++i) b += sA[g][i] * sW2[i * 64 + j];
        sB[g][j] = silu_f(b);
        __syncthreads();
        float c = 0.f;
        #pragma unroll 8
        for (int i = 0; i < 64; ++i) c += sB[g][i] * sW3[i * 64 + j];
        const float h = silu_f(c);
        const u16 hi = f2b(h);
        u16* H = ws + OFF_H2 + (size_t)n * 128;
        H[j]      = hi;
        H[64 + j] = f2b(h - b2f(hi));
        __syncthreads();
    }
}

// ---------------- prep1: per-node y0/y1 -> A y-columns ----------------
__global__ __launch_bounds__(256)
void prep1(const float* nf, const float* na, const float* wsc0, const float* wsc1, u16* ws)
{
    const int t = threadIdx.x & 127;
    const int n = blockIdx.x * 2 + (threadIdx.x >> 7);

    int e = 0;
    #pragma unroll
    for (int i = 0; i < 10; ++i) if (na[(size_t)n * 10 + i] > 0.5f) e = i;

    const float4 x = *(const float4*)(nf + (size_t)n * 512 + t * 4);
    const float x0 = x.x, xa = x.y, xb = x.z, xc = x.w;
    const float n1 = xa * xa + xb * xb + xc * xc;
    const float x2 = x0 * x0;

    const float y0 = wsc0[(e * 5 + 0) * 128 + t] * x0
                   + wsc0[(e * 5 + 1) * 128 + t] * x2
                   + wsc0[(e * 5 + 2) * 128 + t] * n1
                   + wsc0[(e * 5 + 3) * 128 + t] * (x2 * x0)
                   + wsc0[(e * 5 + 4) * 128 + t] * (x0 * n1);
    const float s1 = wsc1[(e * 4 + 0) * 128 + t]
                   + wsc1[(e * 4 + 1) * 128 + t] * x0
                   + wsc1[(e * 4 + 2) * 128 + t] * x2
                   + wsc1[(e * 4 + 3) * 128 + t] * n1;

    ws[OFF_A0 + (size_t)n * 384 + 256 + t]            = f2b(y0);
    ws[OFF_A1 + 0 * A1SZ + (size_t)n * 384 + 256 + t] = f2b(s1 * xa);
    ws[OFF_A1 + 1 * A1SZ + (size_t)n * 384 + 256 + t] = f2b(s1 * xb);
    ws[OFF_A1 + 2 * A1SZ + (size_t)n * 384 + 256 + t] = f2b(s1 * xc);
}

// ---------------- tpwA: MFMA h2 @ w4T2, epilogue writes A products ----------------
__global__ __launch_bounds__(256)
void tpwA(u16* ws, const float* ma)
{
    const int w  = threadIdx.x >> 6;     // 0:wa 1:wb 2:wc 3:wd
    const int l  = threadIdx.x & 63;
    const int lr = l & 15, lk = l >> 4;
    const int n0 = blockIdx.x * 16;

    f32x4 acc[8];
    #pragma unroll
    for (int i = 0; i < 8; ++i) acc[i] = (f32x4){0.f, 0.f, 0.f, 0.f};

    const u16* Ah = ws + OFF_H2  + (size_t)(n0 + lr) * 128 + lk * 8;
    const u16* Bc = ws + OFF_W4T + (size_t)(w * 128 + lr) * 128 + lk * 8;

    #pragma unroll
    for (int kk = 0; kk < 128; kk += 32) {
        const short8 a = *(const short8*)(Ah + kk);
        #pragma unroll
        for (int ct = 0; ct < 8; ++ct) {
            const short8 b = *(const short8*)(Bc + (size_t)ct * 2048 + kk); // +16 cols
            acc[ct] = __builtin_amdgcn_mfma_f32_16x16x32_bf16(a, b, acc[ct], 0, 0, 0);
        }
    }

    #pragma unroll
    for (int ct = 0; ct < 8; ++ct) {
        #pragma unroll
        for (int i = 0; i < 4; ++i) {
            const int c = ct * 16 + lr;
            const int n = n0 + lk * 4 + i;
            const float tv = acc[ct][i];
            const float4 mq = *(const float4*)(ma + (size_t)n * 4);
            if (w == 0) {
                const float y0 = b2f(ws[OFF_A0 + (size_t)n * 384 + 256 + c]);
                ws[OFF_A0 + (size_t)n * 384 + c] = f2b(tv * y0 * mq.x);
            } else if (w == 1) {
                const float y1a = b2f(ws[OFF_A1 + 0 * A1SZ + (size_t)n * 384 + 256 + c]);
                const float y1b = b2f(ws[OFF_A1 + 1 * A1SZ + (size_t)n * 384 + 256 + c]);
                const float y1c = b2f(ws[OFF_A1 + 2 * A1SZ + (size_t)n * 384 + 256 + c]);
                ws[OFF_A0 + (size_t)n * 384 + 128 + c] =
                    f2b(tv * (y1a * mq.y + y1b * mq.z + y1c * mq.w));
            } else if (w == 2) {
                const float y0 = b2f(ws[OFF_A0 + (size_t)n * 384 + 256 + c]);
                ws[OFF_A1 + 0 * A1SZ + (size_t)n * 384 + c] = f2b(tv * y0 * mq.y);
                ws[OFF_A1 + 1 * A1SZ + (size_t)n * 384 + c] = f2b(tv * y0 * mq.z);
                ws[OFF_A1 + 2 * A1SZ + (size_t)n * 384 + c] = f2b(tv * y0 * mq.w);
            } else {
                #pragma unroll
                for (int m = 0; m < 3; ++m) {
                    const float y1m = b2f(ws[OFF_A1 + m * A1SZ + (size_t)n * 384 + 256 + c]);
                    ws[OFF_A1 + m * A1SZ + (size_t)n * 384 + 128 + c] = f2b(tv * y1m * mq.x);
                }
            }
        }
    }
}

// ---------------- gemm0: o0 = A0 @ WT0 + sc[:, :128] ----------------
__global__ __launch_bounds__(256)
void gemm0(const u16* ws, const float* sc, float* out)
{
    const int w  = threadIdx.x >> 6;
    const int l  = threadIdx.x & 63;
    const int lr = l & 15, lk = l >> 4;
    const int r0 = blockIdx.x * 128 + w * 32;

    f32x4 acc[2][8];
    #pragma unroll
    for (int a = 0; a < 2; ++a)
        #pragma unroll
        for (int b = 0; b < 8; ++b) acc[a][b] = (f32x4){0.f, 0.f, 0.f, 0.f};

    const u16* Ar0 = ws + OFF_A0 + (size_t)(r0 + lr) * 384 + lk * 8;
    const u16* Ar1 = Ar0 + 16 * 384;
    const u16* Bc  = ws + OFF_WT0 + (size_t)lr * 384 + lk * 8;

    for (int kk = 0; kk < 384; kk += 32) {
        const short8 a0 = *(const short8*)(Ar0 + kk);
        const short8 a1 = *(const short8*)(Ar1 + kk);
        #pragma unroll
        for (int ct = 0; ct < 8; ++ct) {
            const short8 b = *(const short8*)(Bc + (size_t)ct * 6144 + kk);
            acc[0][ct] = __builtin_amdgcn_mfma_f32_16x16x32_bf16(a0, b, acc[0][ct], 0, 0, 0);
            acc[1][ct] = __builtin_amdgcn_mfma_f32_16x16x32_bf16(a1, b, acc[1][ct], 0, 0, 0);
        }
    }

    #pragma unroll
    for (int rt = 0; rt < 2; ++rt)
        #pragma unroll
        for (int ct = 0; ct < 8; ++ct)
            #pragma unroll
            for (int i = 0; i < 4; ++i) {
                const int row = r0 + rt * 16 + lk * 4 + i;
                const size_t idx = (size_t)row * 512 + ct * 16 + lr;
                out[idx] = acc[rt][ct][i] + sc[idx];
            }
}

// ---------------- gemm1: o1 = A1m @ WT1 + sc[:, 128:], LDS-staged coalesced write ----------------
__global__ __launch_bounds__(256)
void gemm1(const u16* ws, const float* sc, float* out)
{
    __shared__ __align__(16) float sOut[4][16][192];
    const int w  = threadIdx.x >> 6;
    const int l  = threadIdx.x & 63;
    const int lr = l & 15, lk = l >> 4;
    const int rt = w >> 1, ch = w & 1;
    const int nb = blockIdx.x * 32 + rt * 16;

    f32x4 acc[3][4];
    #pragma unroll
    for (int m = 0; m < 3; ++m)
        #pragma unroll
        for (int c = 0; c < 4; ++c) acc[m][c] = (f32x4){0.f, 0.f, 0.f, 0.f};

    const u16* A0p = ws + OFF_A1 + 0 * A1SZ + (size_t)(nb + lr) * 384 + lk * 8;
    const u16* A1p = ws + OFF_A1 + 1 * A1SZ + (size_t)(nb + lr) * 384 + lk * 8;
    const u16* A2p = ws + OFF_A1 + 2 * A1SZ + (size_t)(nb + lr) * 384 + lk * 8;
    const u16* Bc  = ws + OFF_WT1 + (size_t)(ch * 64 + lr) * 384 + lk * 8;

    for (int kk = 0; kk < 384; kk += 32) {
        const short8 a0 = *(const short8*)(A0p + kk);
        const short8 a1 = *(const short8*)(A1p + kk);
        const short8 a2 = *(const short8*)(A2p + kk);
        #pragma unroll
        for (int ct = 0; ct < 4; ++ct) {
            const short8 b = *(const short8*)(Bc + (size_t)ct * 6144 + kk);
            acc[0][ct] = __builtin_amdgcn_mfma_f32_16x16x32_bf16(a0, b, acc[0][ct], 0, 0, 0);
            acc[1][ct] = __builtin_amdgcn_mfma_f32_16x16x32_bf16(a1, b, acc[1][ct], 0, 0, 0);
            acc[2][ct] = __builtin_amdgcn_mfma_f32_16x16x32_bf16(a2, b, acc[2][ct], 0, 0, 0);
        }
    }

    // stage: sOut[w][row][(d-local)*3+m]  (wave-private slice, no barrier needed)
    #pragma unroll
    for (int ct = 0; ct < 4; ++ct)
        #pragma unroll
        for (int i = 0; i < 4; ++i) {
            const int dl = ct * 16 + lr;          // 0..63 local d
            const int r  = lk * 4 + i;
            sOut[w][r][dl * 3 + 0] = acc[0][ct][i];
            sOut[w][r][dl * 3 + 1] = acc[1][ct][i];
            sOut[w][r][dl * 3 + 2] = acc[2][ct][i];
        }

    // coalesced write-back: per node-row, 192 consecutive floats at 128 + ch*192
    for (int r = 0; r < 16; ++r) {
        if (l < 48) {
            const size_t base = (size_t)(nb + r) * 512 + 128 + ch * 192 + l * 4;
            const float4 v = *(const float4*)&sOut[w][r][l * 4];
            const float4 s = *(const float4*)(sc + base);
            float4 o; o.x = v.x + s.x; o.y = v.y + s.y; o.z = v.z + s.z; o.w = v.w + s.w;
            *(float4*)(out + base) = o;
        }
    }
}

// ================= legacy round-8 path (proven @910us) =================
__global__ __launch_bounds__(256)
void prep8(const float* nf, const float* na, const float* inv, const float* ma,
           const float* wsc0, const float* wsc1,
           const float* w1, const float* w2, const float* w3, const float* w4,
           u16* ws)
{
    const int t  = threadIdx.x;
    const int ty = threadIdx.y;
    const int n  = blockIdx.x * 2 + ty;
    __shared__ float sH[2][64], sG[2][64];

    int e = 0;
    #pragma unroll
    for (int i = 0; i < 10; ++i) if (na[(size_t)n * 10 + i] > 0.5f) e = i;

    const float4 x = *(const float4*)(nf + (size_t)n * 512 + t * 4);
    const float x0 = x.x, xa = x.y, xb = x.z, xc = x.w;
    const float n1 = xa * xa + xb * xb + xc * xc;
    const float x2 = x0 * x0;

    const float y0 = wsc0[(e*5+0)*128+t]*x0 + wsc0[(e*5+1)*128+t]*x2 + wsc0[(e*5+2)*128+t]*n1
                   + wsc0[(e*5+3)*128+t]*(x2*x0) + wsc0[(e*5+4)*128+t]*(x0*n1);
    const float s1 = wsc1[(e*4+0)*128+t] + wsc1[(e*4+1)*128+t]*x0
                   + wsc1[(e*4+2)*128+t]*x2 + wsc1[(e*4+3)*128+t]*n1;
    const float y1a = s1*xa, y1b = s1*xb, y1c = s1*xc;

    if (t < 64) { float a=0.f;
        #pragma unroll
        for (int i=0;i<16;++i) a += inv[(size_t)n*16+i]*w1[i*64+t]; sH[ty][t]=silu_f(a); }
    __syncthreads();
    if (t < 64) { float a=0.f; for (int i=0;i<64;++i) a += sH[ty][i]*w2[i*64+t]; sG[ty][t]=silu_f(a); }
    __syncthreads();
    if (t < 64) { float a=0.f; for (int i=0;i<64;++i) a += sG[ty][i]*w3[i*64+t]; sH[ty][t]=silu_f(a); }
    __syncthreads();

    float wa=0.f, wb=0.f, wc=0.f, wd=0.f;
    for (int i = 0; i < 64; ++i) {
        const float h = sH[ty][i];
        wa += h*w4[(size_t)i*512+t]; wb += h*w4[(size_t)i*512+128+t];
        wc += h*w4[(size_t)i*512+256+t]; wd += h*w4[(size_t)i*512+384+t];
    }
    const float a0 = ma[(size_t)n*4+0], q1 = ma[(size_t)n*4+1], q2 = ma[(size_t)n*4+2], q3 = ma[(size_t)n*4+3];
    const float dt = xa*q1 + xb*q2 + xc*q3;

    u16* A0 = ws + A0_OFF8 + (size_t)n * 384;
    A0[t] = f2b(wa*y0*a0); A0[128+t] = f2b(wb*s1*dt); A0[256+t] = f2b(y0);
    u16* A1 = ws + A1_OFF8 + (size_t)(n * 3) * 384;
    A1[t] = f2b(wc*y0*q1); A1[128+t] = f2b(wd*y1a*a0); A1[256+t] = f2b(y1a);
    A1[384+t] = f2b(wc*y0*q2); A1[384+128+t] = f2b(wd*y1b*a0); A1[384+256+t] = f2b(y1b);
    A1[768+t] = f2b(wc*y0*q3); A1[768+128+t] = f2b(wd*y1c*a0); A1[768+256+t] = f2b(y1c);
}

__global__ __launch_bounds__(256)
void gemm8(const u16* ws, const float* sc, float* out)
{
    const int w = threadIdx.x >> 6, l = threadIdx.x & 63;
    const int lr = l & 15, lk = l >> 4;
    const int blk = blockIdx.x;
    const bool isA0 = blk < 512;
    const size_t Abase = isA0 ? (A0_OFF8 + (size_t)blk * 128 * 384)
                              : (A1_OFF8 + (size_t)(blk - 512) * 128 * 384);
    const u16* WT = ws + (isA0 ? OFF_WT0 : OFF_WT1);

    f32x4 acc[2][8];
    #pragma unroll
    for (int a = 0; a < 2; ++a)
        #pragma unroll
        for (int b = 0; b < 8; ++b) acc[a][b] = (f32x4){0.f,0.f,0.f,0.f};

    const u16* Ar0 = ws + Abase + (size_t)(w * 32 + lr) * 384 + lk * 8;
    const u16* Ar1 = Ar0 + 16 * 384;
    const u16* Bc  = WT + (size_t)lr * 384 + lk * 8;

    for (int kk = 0; kk < 384; kk += 32) {
        const short8 a0 = *(const short8*)(Ar0 + kk);
        const short8 a1 = *(const short8*)(Ar1 + kk);
        #pragma unroll
        for (int ct = 0; ct < 8; ++ct) {
            const short8 b = *(const short8*)(Bc + (size_t)ct * 6144 + kk);
            acc[0][ct] = __builtin_amdgcn_mfma_f32_16x16x32_bf16(a0, b, acc[0][ct], 0, 0, 0);
            acc[1][ct] = __builtin_amdgcn_mfma_f32_16x16x32_bf16(a1, b, acc[1][ct], 0, 0, 0);
        }
    }
    #pragma unroll
    for (int rt = 0; rt < 2; ++rt)
        #pragma unroll
        for (int ct = 0; ct < 8; ++ct)
            #pragma unroll
            for (int i = 0; i < 4; ++i) {
                const int row = blk * 128 + w * 32 + rt * 16 + lk * 4 + i;
                const int d   = ct * 16 + lr;
                const float v = acc[rt][ct][i];
                if (isA0) {
                    const size_t idx = (size_t)row * 512 + d;
                    out[idx] = v + sc[idx];
                } else {
                    const int r = row - NN;
                    const int n = r / 3, m = r - 3 * (r / 3);
                    const size_t idx = (size_t)n * 512 + 128 + 3 * d + m;
                    out[idx] = v + sc[idx];
                }
            }
}

// ================= scalar fallback (round-6, proven) =================
__global__ void epb_fallback(const float* nf, const float* sc, const float* na,
                             const float* inv, const float* ma,
                             const float* wsc0, const float* wsc1,
                             const float* w1, const float* w2, const float* w3,
                             const float* w4, const float* Wl0, const float* Wl1,
                             const float* Wo0, const float* Wo1, float* out)
{
    const int n = blockIdx.x;
    const int t = threadIdx.x;
    __shared__ float sY0[128], sY1a[128], sY1b[128], sY1c[128];
    __shared__ float sM0[256], sM1a[256], sM1b[256], sM1c[256];
    __shared__ float sH[64], sG[64];

    int e = 0;
    #pragma unroll
    for (int i = 0; i < 10; ++i) if (na[(size_t)n * 10 + i] > 0.5f) e = i;

    const float4 x = *(const float4*)(nf + (size_t)n * 512 + t * 4);
    const float x0 = x.x, xa = x.y, xb = x.z, xc = x.w;
    const float n1 = xa*xa + xb*xb + xc*xc;
    const float x2 = x0*x0;
    const float y0 = wsc0[(e*5+0)*128+t]*x0 + wsc0[(e*5+1)*128+t]*x2 + wsc0[(e*5+2)*128+t]*n1
                   + wsc0[(e*5+3)*128+t]*(x2*x0) + wsc0[(e*5+4)*128+t]*(x0*n1);
    const float s1 = wsc1[(e*4+0)*128+t] + wsc1[(e*4+1)*128+t]*x0
                   + wsc1[(e*4+2)*128+t]*x2 + wsc1[(e*4+3)*128+t]*n1;
    const float y1a = s1*xa, y1b = s1*xb, y1c = s1*xc;
    sY0[t]=y0; sY1a[t]=y1a; sY1b[t]=y1b; sY1c[t]=y1c;

    if (t<64){float a=0.f;for(int i=0;i<16;++i)a+=inv[(size_t)n*16+i]*w1[i*64+t];sH[t]=silu_f(a);}
    __syncthreads();
    if (t<64){float a=0.f;for(int i=0;i<64;++i)a+=sH[i]*w2[i*64+t];sG[t]=silu_f(a);}
    __syncthreads();
    if (t<64){float a=0.f;for(int i=0;i<64;++i)a+=sG[i]*w3[i*64+t];sH[t]=silu_f(a);}
    __syncthreads();

    float wa=0.f,wb=0.f,wc=0.f,wd=0.f;
    for (int i=0;i<64;++i){const float h=sH[i];
        wa+=h*w4[(size_t)i*512+t];wb+=h*w4[(size_t)i*512+128+t];
        wc+=h*w4[(size_t)i*512+256+t];wd+=h*w4[(size_t)i*512+384+t];}
    const float a0=ma[(size_t)n*4+0],q1=ma[(size_t)n*4+1],q2=ma[(size_t)n*4+2],q3=ma[(size_t)n*4+3];
    const float dt=xa*q1+xb*q2+xc*q3;
    sM0[t]=wa*y0*a0; sM0[128+t]=wb*s1*dt;
    sM1a[t]=wc*y0*q1; sM1b[t]=wc*y0*q2; sM1c[t]=wc*y0*q3;
    sM1a[128+t]=wd*y1a*a0; sM1b[128+t]=wd*y1b*a0; sM1c[128+t]=wd*y1c*a0;
    __syncthreads();

    const int d=t;
    float o0=sc[(size_t)n*512+d];
    float oa=sc[(size_t)n*512+128+3*d+0];
    float ob=sc[(size_t)n*512+128+3*d+1];
    float oc=sc[(size_t)n*512+128+3*d+2];
    for (int k=0;k<256;++k){const float wl0=Wl0[k*128+d],wl1=Wl1[k*128+d];
        o0+=sM0[k]*wl0;oa+=sM1a[k]*wl1;ob+=sM1b[k]*wl1;oc+=sM1c[k]*wl1;}
    for (int k=0;k<128;++k){const float wo0=Wo0[k*128+d],wo1=Wo1[k*128+d];
        o0+=sY0[k]*wo0;oa+=sY1a[k]*wo1;ob+=sY1b[k]*wo1;oc+=sY1c[k]*wo1;}
    const size_t q=(size_t)n*512;
    out[q+d]=o0; out[q+128+3*d+0]=oa; out[q+128+3*d+1]=ob; out[q+128+3*d+2]=oc;
}

extern "C" void kernel_launch(void* const* d_in, const int* in_sizes, int n_in,
                              void* d_out, int out_size, void* d_ws, size_t ws_size,
                              hipStream_t stream) {
    (void)in_sizes; (void)n_in; (void)out_size;
    const float* nf   = (const float*)d_in[0];
    const float* sc   = (const float*)d_in[1];
    const float* na   = (const float*)d_in[2];
    const float* inv  = (const float*)d_in[3];
    const float* ma   = (const float*)d_in[4];
    const float* wsc0 = (const float*)d_in[5];
    const float* wsc1 = (const float*)d_in[6];
    const float* w1   = (const float*)d_in[7];
    const float* w2   = (const float*)d_in[8];
    const float* w3   = (const float*)d_in[9];
    const float* w4   = (const float*)d_in[10];
    const float* Wl0  = (const float*)d_in[11];
    const float* Wl1  = (const float*)d_in[12];
    const float* Wo0  = (const float*)d_in[13];
    const float* Wo1  = (const float*)d_in[14];
    float* out = (float*)d_out;

    if (ws_size >= WS2_NEEDED) {
        u16* ws = (u16*)d_ws;
        convw<<<256, 384, 0, stream>>>(Wl0, Wl1, Wo0, Wo1, ws);
        convw4<<<512, 128, 0, stream>>>(w4, ws);
        mlp<<<2048, 256, 0, stream>>>(inv, w1, w2, w3, ws);
        prep1<<<NN / 2, 256, 0, stream>>>(nf, na, wsc0, wsc1, ws);
        tpwA<<<4096, 256, 0, stream>>>(ws, ma);
        gemm0<<<512, 256, 0, stream>>>(ws, sc, out);
        gemm1<<<2048, 256, 0, stream>>>(ws, sc, out);
    } else if (ws_size >= WS8_NEEDED) {
        u16* ws = (u16*)d_ws;
        convw<<<256, 384, 0, stream>>>(Wl0, Wl1, Wo0, Wo1, ws);
        prep8<<<NN / 2, dim3(128, 2), 0, stream>>>(nf, na, inv, ma, wsc0, wsc1,
                                                   w1, w2, w3, w4, ws);
        gemm8<<<2048, 256, 0, stream>>>(ws, sc, out);
    } else {
        epb_fallback<<<NN, 128, 0, stream>>>(nf, sc, na, inv, ma, wsc0, wsc1,
                                             w1, w2, w3, w4, Wl0, Wl1, Wo0, Wo1, out);
    }
}